// Round 1
// baseline (171.216 us; speedup 1.0000x reference)
//
#include <hip/hip_runtime.h>
#include <math.h>

// Problem constants (from reference)
constexpr int   kS    = 7;
constexpr int   kNCls = 20;
constexpr int   kB    = 16384;
constexpr float kWCoord = 5.0f;
constexpr float kWNoobj = 0.5f;
constexpr float kEps    = 1e-6f;

// ---------------------------------------------------------------------------
// Block reduce helper: wave-64 shuffle reduce + LDS across waves, then one
// atomicAdd per block. Assumes blockDim.x == 256.
// ---------------------------------------------------------------------------
__device__ __forceinline__ void block_reduce_atomic(float v, float* acc) {
    // wave reduce (width 64)
    #pragma unroll
    for (int off = 32; off > 0; off >>= 1)
        v += __shfl_down(v, off, 64);
    __shared__ float smem[4];
    const int lane = threadIdx.x & 63;
    const int wv   = threadIdx.x >> 6;
    if (lane == 0) smem[wv] = v;
    __syncthreads();
    if (threadIdx.x == 0) {
        float t = smem[0] + smem[1] + smem[2] + smem[3];
        atomicAdd(acc, t);
    }
}

// ---------------------------------------------------------------------------
// Kernel 1: noobj term — 0.5 * sum over all cells of (ch20^2 + ch21^2).
// Fully-coalesced float4 grid-stride over the whole output array; predicate
// each element on (flat_idx % 30) in {20, 21}.
// ---------------------------------------------------------------------------
__global__ void __launch_bounds__(256) noobj_kernel(const float4* __restrict__ o4,
                                                    int n4,
                                                    float* __restrict__ acc) {
    float sum = 0.0f;
    const int stride = gridDim.x * blockDim.x;
    for (int i = blockIdx.x * blockDim.x + threadIdx.x; i < n4; i += stride) {
        float4 v = o4[i];
        int ch0 = (i * 4) % 30;
        float vv[4] = {v.x, v.y, v.z, v.w};
        #pragma unroll
        for (int j = 0; j < 4; ++j) {
            int ch = ch0 + j;
            ch = (ch >= 30) ? (ch - 30) : ch;
            const bool hit = (ch == 20) || (ch == 21);
            const float x = vv[j];
            sum += hit ? x * x : 0.0f;
        }
    }
    sum *= kWNoobj;
    block_reduce_atomic(sum, acc);
}

// ---------------------------------------------------------------------------
// IoU between two center-format boxes (matches reference _iou exactly).
// ---------------------------------------------------------------------------
__device__ __forceinline__ float iou_f(float ax, float ay, float aw, float ah,
                                       float gx, float gy, float gw, float gh) {
    const float ax1 = ax - aw * 0.5f, ax2 = ax + aw * 0.5f;
    const float ay1 = ay - ah * 0.5f, ay2 = ay + ah * 0.5f;
    const float gx1 = gx - gw * 0.5f, gx2 = gx + gw * 0.5f;
    const float gy1 = gy - gh * 0.5f, gy2 = gy + gh * 0.5f;
    const float iw = fmaxf(0.0f, fminf(ax2, gx2) - fmaxf(ax1, gx1));
    const float ih = fmaxf(0.0f, fminf(ay2, gy2) - fmaxf(ay1, gy1));
    const float inter = iw * ih;
    const float uni = aw * ah + gw * gh - inter;
    return inter / (uni + kEps);
}

// ---------------------------------------------------------------------------
// Kernel 2: per-label class + coord + conf terms. One thread per label.
// Gathers one 30-float cell (15x float2, 8B-aligned since cell stride=120B).
// ---------------------------------------------------------------------------
__global__ void __launch_bounds__(256) label_kernel(const float* __restrict__ out,
                                                    const float* __restrict__ labels,
                                                    int nl,
                                                    float* __restrict__ acc) {
    const int l = blockIdx.x * blockDim.x + threadIdx.x;
    float sum = 0.0f;
    if (l < nl) {
        // labels row: [b, c, cx, cy, w, h]; rows are 24B (8-aligned) -> 3x float2
        const float2* lab2 = reinterpret_cast<const float2*>(labels + (size_t)l * 6);
        const float2 l0 = lab2[0];
        const float2 l1 = lab2[1];
        const float2 l2 = lab2[2];
        const int   b  = (int)l0.x;
        const int   c  = (int)l0.y;
        const float gx = l1.x, gy = l1.y, gw = l2.x, gh = l2.y;

        const float rowf = floorf(gx * (float)kS);
        const float colf = floorf(gy * (float)kS);
        const int row = (int)rowf;
        const int col = (int)colf;

        // gather the 30-float cell (byte offset 120*cell, always 8B aligned)
        const float* p = out + ((size_t)b * (kS * kS) + row * kS + col) * 30;
        const float2* p2 = reinterpret_cast<const float2*>(p);
        float pv[30];
        #pragma unroll
        for (int j = 0; j < 15; ++j) {
            const float2 t = p2[j];
            pv[2 * j]     = t.x;
            pv[2 * j + 1] = t.y;
        }

        // class loss: sum_{j<20} (p[j] - onehot[j])^2
        float cl = 0.0f;
        #pragma unroll
        for (int j = 0; j < kNCls; ++j) {
            const float d = pv[j] - ((j == c) ? 1.0f : 0.0f);
            cl += d * d;
        }

        // IoUs of the two predictors (converted to global coords) vs gt
        const float inv_s = 1.0f / (float)kS;
        const float b1x = (rowf + pv[22]) * inv_s;  // note: ref divides by S
        const float b1y = (colf + pv[23]) * inv_s;
        const float b2x = (rowf + pv[26]) * inv_s;
        const float b2y = (colf + pv[27]) * inv_s;
        // match reference division exactly: (rowf + x)/S  — use true division
        const float g1x = (rowf + pv[22]) / (float)kS;
        const float g1y = (colf + pv[23]) / (float)kS;
        const float g2x = (rowf + pv[26]) / (float)kS;
        const float g2y = (colf + pv[27]) / (float)kS;
        (void)b1x; (void)b1y; (void)b2x; (void)b2y;

        const float iou1 = iou_f(g1x, g1y, pv[24], pv[25], gx, gy, gw, gh);
        const float iou2 = iou_f(g2x, g2y, pv[28], pv[29], gx, gy, gw, gh);
        const bool use1 = (iou1 >= iou2);

        // coord loss
        const float gtx_cell = gx * (float)kS - rowf;
        const float gty_cell = gy * (float)kS - colf;
        const float px = use1 ? pv[22] : pv[26];
        const float py = use1 ? pv[23] : pv[27];
        const float pw = use1 ? pv[24] : pv[28];
        const float ph = use1 ? pv[25] : pv[29];
        const float dx = px - gtx_cell;
        const float dy = py - gty_cell;
        const float dw = sqrtf(pw + kEps) - sqrtf(gw + kEps);
        const float dh = sqrtf(ph + kEps) - sqrtf(gh + kEps);
        const float coord = kWCoord * (dx * dx + dy * dy + dw * dw + dh * dh);

        // conf loss (per-label part; noobj handled in kernel 1)
        const float cp = use1 ? pv[20] : pv[21];
        const float ct = use1 ? iou1 : iou2;
        const float conf = (cp - ct) * (cp - ct) - kWNoobj * cp * cp;

        sum = cl + coord + conf;
    }
    block_reduce_atomic(sum, acc);
}

// ---------------------------------------------------------------------------
// Kernel 3: finalize — divide by batch size (exact: 1/16384 is a power of 2).
// ---------------------------------------------------------------------------
__global__ void finalize_kernel(const float* __restrict__ acc, float* __restrict__ out) {
    out[0] = acc[0] * (1.0f / (float)kB);
}

extern "C" void kernel_launch(void* const* d_in, const int* in_sizes, int n_in,
                              void* d_out, int out_size, void* d_ws, size_t ws_size,
                              hipStream_t stream) {
    const float* output = (const float*)d_in[0];   // (B, 7, 7, 30) fp32
    const float* labels = (const float*)d_in[1];   // (NL, 6) fp32
    float* out = (float*)d_out;
    float* acc = (float*)d_ws;

    const int n_out_elems = in_sizes[0];           // B*7*7*30 = 24,084,480 (div by 4)
    const int n4 = n_out_elems / 4;
    const int nl = in_sizes[1] / 6;                // 131072

    // zero the accumulator (d_ws is poisoned 0xAA before every launch)
    hipMemsetAsync(acc, 0, sizeof(float), stream);

    // Kernel 1: dense noobj reduction, grid-stride, ~8 blocks/CU
    const int blocks1 = 2048;
    noobj_kernel<<<blocks1, 256, 0, stream>>>((const float4*)output, n4, acc);

    // Kernel 2: one thread per label
    const int blocks2 = (nl + 255) / 256;
    label_kernel<<<blocks2, 256, 0, stream>>>(output, labels, nl, acc);

    // Kernel 3: finalize
    finalize_kernel<<<1, 1, 0, stream>>>(acc, out);
}

// Round 2
// 146.290 us; speedup vs baseline: 1.1704x; 1.1704x over previous
//
#include <hip/hip_runtime.h>
#include <math.h>

// Problem constants (from reference)
constexpr int   kS      = 7;
constexpr int   kNCls   = 20;
constexpr int   kB      = 16384;
constexpr int   kNCells = kB * kS * kS;   // 802,816
constexpr float kWCoord = 5.0f;
constexpr float kWNoobj = 0.5f;
constexpr float kEps    = 1e-6f;

constexpr int kBlocks = 2048;             // ~8 blocks/CU on 256 CUs
constexpr int kThreads = 256;

// ---------------------------------------------------------------------------
// Wave-64 + LDS block reduce. Returns full block sum on thread 0.
// ---------------------------------------------------------------------------
__device__ __forceinline__ float block_reduce(float v) {
    #pragma unroll
    for (int off = 32; off > 0; off >>= 1)
        v += __shfl_down(v, off, 64);
    __shared__ float smem[kThreads / 64];
    const int lane = threadIdx.x & 63;
    const int wv   = threadIdx.x >> 6;
    if (lane == 0) smem[wv] = v;
    __syncthreads();
    float t = 0.0f;
    if (threadIdx.x == 0) {
        #pragma unroll
        for (int i = 0; i < kThreads / 64; ++i) t += smem[i];
    }
    return t;
}

// ---------------------------------------------------------------------------
// IoU between two center-format boxes (matches reference _iou exactly).
// ---------------------------------------------------------------------------
__device__ __forceinline__ float iou_f(float ax, float ay, float aw, float ah,
                                       float gx, float gy, float gw, float gh) {
    const float ax1 = ax - aw * 0.5f, ax2 = ax + aw * 0.5f;
    const float ay1 = ay - ah * 0.5f, ay2 = ay + ah * 0.5f;
    const float gx1 = gx - gw * 0.5f, gx2 = gx + gw * 0.5f;
    const float gy1 = gy - gh * 0.5f, gy2 = gy + gh * 0.5f;
    const float iw = fmaxf(0.0f, fminf(ax2, gx2) - fmaxf(ax1, gx1));
    const float ih = fmaxf(0.0f, fminf(ay2, gy2) - fmaxf(ay1, gy1));
    const float inter = iw * ih;
    const float uni = aw * ah + gw * gh - inter;
    return inter / (uni + kEps);
}

// ---------------------------------------------------------------------------
// Fused kernel: dense noobj term (ch20/21 only, strided float2 loads) + the
// per-label class/coord/conf terms. Per-block partial sum -> partials[block].
// No atomics, no pre-zeroed accumulator needed.
// ---------------------------------------------------------------------------
__global__ void __launch_bounds__(kThreads)
fused_kernel(const float* __restrict__ out,
             const float* __restrict__ labels,
             int nl,
             float* __restrict__ partials) {
    const int tid    = blockIdx.x * blockDim.x + threadIdx.x;
    const int stride = gridDim.x * blockDim.x;
    float sum = 0.0f;

    // --- Part A: noobj — only channels 20,21 of each cell (8B of each 120B) ---
    for (int c = tid; c < kNCells; c += stride) {
        const float2 v = *reinterpret_cast<const float2*>(out + (size_t)c * 30 + 20);
        sum += kWNoobj * (v.x * v.x + v.y * v.y);
    }

    // --- Part B: per-label terms ---
    for (int l = tid; l < nl; l += stride) {
        const float2* lab2 = reinterpret_cast<const float2*>(labels + (size_t)l * 6);
        const float2 l0 = lab2[0];
        const float2 l1 = lab2[1];
        const float2 l2 = lab2[2];
        const int   c  = (int)l0.y;
        const float gx = l1.x, gy = l1.y, gw = l2.x, gh = l2.y;

        const float rowf = floorf(gx * (float)kS);
        const float colf = floorf(gy * (float)kS);
        const int row = (int)rowf;
        const int col = (int)colf;
        const int b   = (int)l0.x;

        // gather the 30-float cell (byte offset 120*cell, always 8B aligned)
        const float* p = out + ((size_t)b * (kS * kS) + row * kS + col) * 30;
        const float2* p2 = reinterpret_cast<const float2*>(p);
        float pv[30];
        #pragma unroll
        for (int j = 0; j < 15; ++j) {
            const float2 t = p2[j];
            pv[2 * j]     = t.x;
            pv[2 * j + 1] = t.y;
        }

        // class loss
        float cl = 0.0f;
        #pragma unroll
        for (int j = 0; j < kNCls; ++j) {
            const float d = pv[j] - ((j == c) ? 1.0f : 0.0f);
            cl += d * d;
        }

        // IoUs (global coords: (rowf + x)/S, exact division like reference)
        const float g1x = (rowf + pv[22]) / (float)kS;
        const float g1y = (colf + pv[23]) / (float)kS;
        const float g2x = (rowf + pv[26]) / (float)kS;
        const float g2y = (colf + pv[27]) / (float)kS;

        const float iou1 = iou_f(g1x, g1y, pv[24], pv[25], gx, gy, gw, gh);
        const float iou2 = iou_f(g2x, g2y, pv[28], pv[29], gx, gy, gw, gh);
        const bool use1 = (iou1 >= iou2);

        // coord loss
        const float gtx_cell = gx * (float)kS - rowf;
        const float gty_cell = gy * (float)kS - colf;
        const float px = use1 ? pv[22] : pv[26];
        const float py = use1 ? pv[23] : pv[27];
        const float pw = use1 ? pv[24] : pv[28];
        const float ph = use1 ? pv[25] : pv[29];
        const float dx = px - gtx_cell;
        const float dy = py - gty_cell;
        const float dw = sqrtf(pw + kEps) - sqrtf(gw + kEps);
        const float dh = sqrtf(ph + kEps) - sqrtf(gh + kEps);
        const float coord = kWCoord * (dx * dx + dy * dy + dw * dw + dh * dh);

        // conf loss (per-label part)
        const float cp = use1 ? pv[20] : pv[21];
        const float ct = use1 ? iou1 : iou2;
        const float conf = (cp - ct) * (cp - ct) - kWNoobj * cp * cp;

        sum += cl + coord + conf;
    }

    const float bsum = block_reduce(sum);
    if (threadIdx.x == 0) partials[blockIdx.x] = bsum;
}

// ---------------------------------------------------------------------------
// Finalize: one block sums the per-block partials and divides by batch size.
// ---------------------------------------------------------------------------
__global__ void __launch_bounds__(kThreads)
finalize_kernel(const float* __restrict__ partials, int n, float* __restrict__ out) {
    float s = 0.0f;
    for (int i = threadIdx.x; i < n; i += blockDim.x) s += partials[i];
    const float t = block_reduce(s);
    if (threadIdx.x == 0) out[0] = t * (1.0f / (float)kB);
}

extern "C" void kernel_launch(void* const* d_in, const int* in_sizes, int n_in,
                              void* d_out, int out_size, void* d_ws, size_t ws_size,
                              hipStream_t stream) {
    const float* output = (const float*)d_in[0];   // (B, 7, 7, 30) fp32
    const float* labels = (const float*)d_in[1];   // (NL, 6) fp32
    float* out = (float*)d_out;
    float* partials = (float*)d_ws;                // kBlocks floats, fully overwritten

    const int nl = in_sizes[1] / 6;                // 131072

    fused_kernel<<<kBlocks, kThreads, 0, stream>>>(output, labels, nl, partials);
    finalize_kernel<<<1, kThreads, 0, stream>>>(partials, kBlocks, out);
}